// Round 7
// baseline (1621.794 us; speedup 1.0000x reference)
//
#include <hip/hip_runtime.h>
#include <cstdint>
#include <cstddef>

// Problem shape (fixed by reference): B=8, S=2048, D=1024, D_FF=1024
#define BB 8
#define SS 2048
#define DD 1024

typedef unsigned short bf16_t;                                  // raw bf16 bits
typedef __attribute__((ext_vector_type(8))) short bf16x8;       // MFMA A/B frag (4 VGPRs)
typedef __attribute__((ext_vector_type(4))) float f32x4;        // MFMA C/D frag
typedef __attribute__((ext_vector_type(4))) short short4v;

#define EPI_BF16   0   // C = bf16(acc + bias), optional ReLU  (bf16 LDS-bounce store)
#define EPI_SCORES 1   // C = mask ? acc*scale : -1e9  (f32, LDS-bounce coalesced)
#define EPI_RESID  2   // C = acc + bias + resid       (f32, LDS-bounce coalesced RMW)

__device__ __forceinline__ bf16_t f2bf(float f) {
  union { float f; unsigned u; } v; v.f = f;
  unsigned r = v.u + 0x7FFFu + ((v.u >> 16) & 1u);   // RNE
  return (bf16_t)(r >> 16);
}

// async global->LDS, 16B per lane. LDS dst must be wave-uniform base + lane*16.
__device__ __forceinline__ void async_copy16(const void* g, void* l) {
  auto gp = reinterpret_cast<unsigned int __attribute__((address_space(1)))*>(
      reinterpret_cast<uintptr_t>(g));
  auto lp = reinterpret_cast<unsigned int __attribute__((address_space(3)))*>(
      reinterpret_cast<uintptr_t>(l));
  __builtin_amdgcn_global_load_lds(gp, lp, 16, 0, 0);
}

// ---------------------------------------------------------------------------
// GEMM parameter block (by-value kernel arg)
// ---------------------------------------------------------------------------
struct GemmP {
  const bf16_t* A;
  const bf16_t* BT;
  void*         C;
  const float*  bias;   // [<=ldc] or null
  const float*  bias2;  // second-half bias (fused QK) or null
  const float*  resid;  // [Z,M,ldc] f32 (EPI_RESID)
  const int*    mask;   // per-batch mask (EPI_SCORES)
  int Mt, Nt, Z, nchunk;
  int K, lda, ldb, ldc;
  long long sA, sB, sC, sMask;
  float scale;
};

// ---------------------------------------------------------------------------
// 256x256 NT GEMM core: identical to r5 (best-known). See r3-r5 comments.
// ---------------------------------------------------------------------------
#define MM(i, j, Af, Bf) \
  acc[i][j] = __builtin_amdgcn_mfma_f32_16x16x32_bf16(Af, Bf, acc[i][j], 0, 0, 0)

#define LDA8(D, MH)                                                        \
  { const char* Ah_ = ldsc + (D) * 65536 + (MH) * 16384;                   \
    aF[0] = *(const bf16x8*)(Ah_ + aro +    0 + s0);                       \
    aF[1] = *(const bf16x8*)(Ah_ + aro + 2048 + s0);                       \
    aF[2] = *(const bf16x8*)(Ah_ + aro + 4096 + s0);                       \
    aF[3] = *(const bf16x8*)(Ah_ + aro + 6144 + s0);                       \
    aF[4] = *(const bf16x8*)(Ah_ + aro +    0 + s1);                       \
    aF[5] = *(const bf16x8*)(Ah_ + aro + 2048 + s1);                       \
    aF[6] = *(const bf16x8*)(Ah_ + aro + 4096 + s1);                       \
    aF[7] = *(const bf16x8*)(Ah_ + aro + 6144 + s1); }

#define LDB4(D, NH, BF)                                                    \
  { const char* Bh_ = ldsc + (D) * 65536 + 32768 + (NH) * 16384;           \
    BF[0] = *(const bf16x8*)(Bh_ + bro +    0 + s0);                       \
    BF[1] = *(const bf16x8*)(Bh_ + bro + 2048 + s0);                       \
    BF[2] = *(const bf16x8*)(Bh_ + bro +    0 + s1);                       \
    BF[3] = *(const bf16x8*)(Bh_ + bro + 2048 + s1); }

#define MFMA16(MH, NH, BF)                                                 \
  __builtin_amdgcn_s_setprio(1);                                           \
  MM((MH)*4+0,(NH)*2+0,aF[0],BF[0]); MM((MH)*4+1,(NH)*2+0,aF[1],BF[0]);    \
  MM((MH)*4+2,(NH)*2+0,aF[2],BF[0]); MM((MH)*4+3,(NH)*2+0,aF[3],BF[0]);    \
  MM((MH)*4+0,(NH)*2+1,aF[0],BF[1]); MM((MH)*4+1,(NH)*2+1,aF[1],BF[1]);    \
  MM((MH)*4+2,(NH)*2+1,aF[2],BF[1]); MM((MH)*4+3,(NH)*2+1,aF[3],BF[1]);    \
  MM((MH)*4+0,(NH)*2+0,aF[4],BF[2]); MM((MH)*4+1,(NH)*2+0,aF[5],BF[2]);    \
  MM((MH)*4+2,(NH)*2+0,aF[6],BF[2]); MM((MH)*4+3,(NH)*2+0,aF[7],BF[2]);    \
  MM((MH)*4+0,(NH)*2+1,aF[4],BF[3]); MM((MH)*4+1,(NH)*2+1,aF[5],BF[3]);    \
  MM((MH)*4+2,(NH)*2+1,aF[6],BF[3]); MM((MH)*4+3,(NH)*2+1,aF[7],BF[3]);    \
  __builtin_amdgcn_s_setprio(0);

template <int EPI, bool RELU>
__device__ __forceinline__ void gemm_core(const GemmP p, int b, char* ldsc)
{
  // ---- XCD swizzle: contiguous idx chunk per XCD ----
  const int Cchunk = (p.Z * p.Mt * p.Nt) >> 3;     // tile count divisible by 8
  int idx = (b & 7) * Cchunk + (b >> 3);
  const int per_z = p.Mt * p.Nt;
  const int z = idx / per_z;  idx -= z * per_z;
  const int per_nc = p.Mt * p.nchunk;
  const int nc = idx / per_nc; idx -= nc * per_nc;
  const int mt = idx / p.nchunk;
  const int nin = idx - mt * p.nchunk;
  const int m0 = mt * 256;
  const int n0 = (nc * p.nchunk + nin) * 256;

  const int tid  = threadIdx.x;
  const int wave = tid >> 6;
  const int lane = tid & 63;
  const int wr   = wave >> 2, wc = wave & 3;       // 2 x 4 wave grid
  const int lr   = lane & 15, quad = lane >> 4;

  const bf16_t* Ab = p.A  + (size_t)z * (size_t)p.sA;
  const bf16_t* Bb = p.BT + (size_t)z * (size_t)p.sB;

  f32x4 acc[8][4];
#pragma unroll
  for (int i = 0; i < 8; ++i)
#pragma unroll
    for (int j = 0; j < 4; ++j)
#pragma unroll
      for (int r = 0; r < 4; ++r) acc[i][j][r] = 0.0f;

  // staging geometry, hoisted. Slot p holds logical k-chunk p^(row&7).
  const bf16_t* gA[2]; const bf16_t* gB[2]; char* lA[2]; char* lB[2];
#pragma unroll
  for (int u = 0; u < 2; ++u) {
    const int c = tid + u * 512;
    const int rl = c >> 3;
    const int csw = (((c & 7) ^ (rl & 7)) << 3);                 // swizzled k-elems
    const int rowA = ((rl & 64) << 1) + (rl & 63);               // rows 0..63,128..191
    const int rowB = ((rl & 96) << 1) + (rl & 31);
    gA[u] = Ab + (size_t)(m0 + rowA) * p.lda + csw;
    gB[u] = Bb + (size_t)(n0 + rowB) * p.ldb + csw;
    lA[u] = ldsc + c * 16;
    lB[u] = ldsc + 32768 + c * 16;
  }
  const int ldA64 = p.lda << 6, ldB64 = p.ldb << 5;

  auto stageA = [&](int d, int mh, int kt) {
    const int go = mh * ldA64 + kt;
    const int lo = d * 65536 + mh * 16384;
#pragma unroll
    for (int u = 0; u < 2; ++u) async_copy16(gA[u] + go, lA[u] + lo);
  };
  auto stageB = [&](int d, int nh, int kt) {
    const int go = nh * ldB64 + kt;
    const int lo = d * 65536 + nh * 16384;
#pragma unroll
    for (int u = 0; u < 2; ++u) async_copy16(gB[u] + go, lB[u] + lo);
  };

  // ds_read addressing: logical slot s = ks*4+quad; physical = s^(lr&7)
  const int s0  = ((quad ^ (lr & 7)) << 4);
  const int s1  = s0 ^ 64;
  const int aro = (wr * 64 + lr) << 7;
  const int bro = (wc * 32 + lr) << 7;

  bf16x8 aF[8];
  bf16x8 bF0[4], bF1[4];

  const int NT = p.K >> 6;

  // ---- prologue ----
  stageA(0, 0, 0); stageA(0, 1, 0); stageB(0, 0, 0); stageB(0, 1, 0);
  if (NT > 1) {
    stageA(1, 0, 64); stageB(1, 0, 64);
    asm volatile("s_waitcnt vmcnt(4)" ::: "memory");
  } else {
    asm volatile("s_waitcnt vmcnt(0)" ::: "memory");
  }
  __builtin_amdgcn_s_barrier();

#pragma unroll 2
  for (int t = 0; t < NT; ++t) {
    const int d  = t & 1;
    const int k1 = (t + 1) << 6;
    const int k2 = (t + 2) << 6;

    LDA8(d, 0); LDB4(d, 0, bF0);
    if (t + 1 < NT) stageA(d ^ 1, 1, k1);
    __builtin_amdgcn_s_barrier();
    MFMA16(0, 0, bF0);

    LDB4(d, 1, bF1);
    if (t + 1 < NT) stageB(d ^ 1, 1, k1);
    __builtin_amdgcn_s_barrier();
    MFMA16(0, 1, bF1);

    LDA8(d, 1);
    if (t + 2 < NT) stageA(d, 0, k2);
    __builtin_amdgcn_s_barrier();
    MFMA16(1, 1, bF1);

    if (t + 2 < NT) {
      stageB(d, 0, k2);
      asm volatile("s_waitcnt vmcnt(4)" ::: "memory");
    } else {
      asm volatile("s_waitcnt vmcnt(0)" ::: "memory");
    }
    __builtin_amdgcn_s_barrier();
    MFMA16(1, 0, bF0);
  }

  // ---- epilogue ----  (C/D layout: col = lane&15, row = quad*4 + r)
  if constexpr (EPI == EPI_BF16) {
    char* Wb = ldsc + wave * 16384;
#pragma unroll
    for (int i = 0; i < 8; ++i) {
      const int mb = (i >> 2) * 64 + (i & 3) * 16 + quad * 4;     // + r
#pragma unroll
      for (int j = 0; j < 4; ++j) {
        const int nl = (j >> 1) * 32 + (j & 1) * 16 + lr;         // 0..63
        const int gn = n0 + wc * 64 + nl;
        const float bv = (p.bias2 && gn >= 1024) ? p.bias2[gn - 1024]
                       : (p.bias ? p.bias[gn] : 0.0f);
#pragma unroll
        for (int r = 0; r < 4; ++r) {
          float v = acc[i][j][r] + bv;
          if (RELU) v = fmaxf(v, 0.0f);
          const int m = mb + r;
          const int nb = nl * 2;
          const int phys = (m << 7) + (((nb & ~15) ^ ((m & 7) << 4)) | (nb & 15));
          *(bf16_t*)(Wb + phys) = f2bf(v);
        }
      }
    }
    asm volatile("s_waitcnt lgkmcnt(0)" ::: "memory");
    bf16_t* Cb = (bf16_t*)p.C + (size_t)z * (size_t)p.sC
               + (size_t)(m0 + wr * 128) * p.ldc + (n0 + wc * 64);
#pragma unroll
    for (int q = 0; q < 16; ++q) {
      const int m = q * 8 + (lane >> 3);
      const int c = lane & 7;
      const bf16x8 vv = *(const bf16x8*)(Wb + (m << 7) + (((c ^ (m & 7)) << 4)));
      *(bf16x8*)(Cb + (size_t)m * p.ldc + c * 8) = vv;
    }
  } else {
    char* Wb = ldsc + wave * 16384;
#pragma unroll
    for (int hh = 0; hh < 2; ++hh) {
#pragma unroll
      for (int ii = 0; ii < 4; ++ii) {
        const int i = hh * 4 + ii;
        const int ml = ii * 16 + quad * 4;                        // + r
#pragma unroll
        for (int j = 0; j < 4; ++j) {
          const int nl = (j >> 1) * 32 + (j & 1) * 16 + lr;       // 0..63
          const int gn = n0 + wc * 64 + nl;
          float addv = 0.0f; int mk = 1;
          if constexpr (EPI == EPI_RESID) addv = p.bias ? p.bias[gn] : 0.0f;
          if constexpr (EPI == EPI_SCORES)
            mk = p.mask[(size_t)z * (size_t)p.sMask + gn];
#pragma unroll
          for (int r = 0; r < 4; ++r) {
            const int m = ml + r;
            float v = acc[i][j][r];
            if constexpr (EPI == EPI_SCORES) v = mk ? v * p.scale : -1e9f;
            else v += addv;
            const int nph = nl ^ (((m >> 2) & 3) << 2);
            *(float*)(Wb + m * 256 + nph * 4) = v;
          }
        }
      }
      asm volatile("s_waitcnt lgkmcnt(0)" ::: "memory");
      const int mb = m0 + wr * 128 + hh * 64;
      const int gn0 = n0 + wc * 64 + lr * 4;
#pragma unroll
      for (int q = 0; q < 16; ++q) {
        const int m = q * 4 + quad;
        const int nph = (lr * 4) ^ (((m >> 2) & 3) << 2);
        f32x4 v = *(const f32x4*)(Wb + m * 256 + nph * 4);
        const size_t off = (size_t)z * (size_t)p.sC
                         + (size_t)(mb + m) * p.ldc + gn0;
        if constexpr (EPI == EPI_RESID) {
          const f32x4 rv = *(const f32x4*)(p.resid + off);
          v = v + rv;
        }
        *(f32x4*)((float*)p.C + off) = v;
      }
      if (hh == 0) { asm volatile("s_waitcnt lgkmcnt(0)" ::: "memory"); }
    }
  }
}

// rep: DIAGNOSTIC repeat count. All repeated stages are idempotent (outputs do
// not alias inputs), so results are unchanged; dispatch dur multiplies by rep,
// lifting the stage into rocprof's top-5 with its own counters.
// Single-stage cost = extra_dur / (rep - 1).
template <int EPI, bool RELU>
__global__ __launch_bounds__(512, 2)
void gemm256(GemmP p, int rep)
{
  __shared__ __align__(16) char lds_[131072];
  for (int r = 0; r < rep; ++r) {
    if (r) __syncthreads();                 // LDS reuse hazard between reps
    gemm_core<EPI, RELU>(p, blockIdx.x, lds_);
  }
}

// merged launch: blocks [0,n1) run EPI_SCORES on p1; [n1,...) EPI_BF16 on p2.
__global__ __launch_bounds__(512, 2)
void gemm_pair(GemmP p1, int n1, GemmP p2, int rep)
{
  __shared__ __align__(16) char lds_[131072];
  for (int r = 0; r < rep; ++r) {
    if (r) __syncthreads();
    if ((int)blockIdx.x < n1) gemm_core<EPI_SCORES, false>(p1, blockIdx.x, lds_);
    else                      gemm_core<EPI_BF16,   false>(p2, blockIdx.x - n1, lds_);
  }
}

// ---------------------------------------------------------------------------
// Shared device bodies: LayerNorm row, softmax row, 32x32 tile transpose.
// ---------------------------------------------------------------------------
__device__ __forceinline__ void ln_body(const float* __restrict__ x,
                                        const float* __restrict__ g,
                                        const float* __restrict__ b,
                                        bf16_t* __restrict__ out,
                                        int row, int t, float* red)
{
  const int wave = t >> 6, lane = t & 63;
  const float4 v = ((const float4*)(x + (size_t)row * DD))[t];

  float s = v.x + v.y + v.z + v.w;
#pragma unroll
  for (int o = 32; o > 0; o >>= 1) s += __shfl_down(s, o);
  if (lane == 0) red[wave] = s;
  __syncthreads();
  const float mu = (red[0] + red[1] + red[2] + red[3]) * (1.0f / DD);

  const float d0 = v.x - mu, d1 = v.y - mu, d2 = v.z - mu, d3 = v.w - mu;
  float ss = d0 * d0 + d1 * d1 + d2 * d2 + d3 * d3;
#pragma unroll
  for (int o = 32; o > 0; o >>= 1) ss += __shfl_down(ss, o);
  if (lane == 0) red[4 + wave] = ss;
  __syncthreads();
  const float var = (red[4] + red[5] + red[6] + red[7]) * (1.0f / DD);
  const float rs  = rsqrtf(var + 1e-5f);

  const float4 gg = ((const float4*)g)[t];
  const float4 bb = ((const float4*)b)[t];
  short4v o;
  o.x = (short)f2bf(d0 * rs * gg.x + bb.x);
  o.y = (short)f2bf(d1 * rs * gg.y + bb.y);
  o.z = (short)f2bf(d2 * rs * gg.z + bb.z);
  o.w = (short)f2bf(d3 * rs * gg.w + bb.w);
  *(short4v*)(out + (size_t)row * DD + t * 4) = o;
}

__global__ __launch_bounds__(256)
void softmax_kernel(float* __restrict__ w, bf16_t* __restrict__ wb)
{
  __shared__ float red[8];
  const size_t rowoff = (size_t)blockIdx.x * SS;
  float* p = w + rowoff;
  const int t = threadIdx.x;
  const int wave = t >> 6, lane = t & 63;
  float4 v0 = ((float4*)p)[t];
  float4 v1 = ((float4*)p)[t + 256];

  float m = fmaxf(fmaxf(fmaxf(v0.x, v0.y), fmaxf(v0.z, v0.w)),
                  fmaxf(fmaxf(v1.x, v1.y), fmaxf(v1.z, v1.w)));
#pragma unroll
  for (int o = 32; o > 0; o >>= 1) m = fmaxf(m, __shfl_down(m, o));
  if (lane == 0) red[wave] = m;
  __syncthreads();
  m = fmaxf(fmaxf(red[0], red[1]), fmaxf(red[2], red[3]));

  v0.x = __expf(v0.x - m); v0.y = __expf(v0.y - m);
  v0.z = __expf(v0.z - m); v0.w = __expf(v0.w - m);
  v1.x = __expf(v1.x - m); v1.y = __expf(v1.y - m);
  v1.z = __expf(v1.z - m); v1.w = __expf(v1.w - m);

  float s = v0.x + v0.y + v0.z + v0.w + v1.x + v1.y + v1.z + v1.w;
#pragma unroll
  for (int o = 32; o > 0; o >>= 1) s += __shfl_down(s, o);
  if (lane == 0) red[4 + wave] = s;
  __syncthreads();
  const float inv = 1.0f / (red[4] + red[5] + red[6] + red[7]);

  v0.x *= inv; v0.y *= inv; v0.z *= inv; v0.w *= inv;
  v1.x *= inv; v1.y *= inv; v1.z *= inv; v1.w *= inv;
  ((float4*)p)[t] = v0;
  ((float4*)p)[t + 256] = v1;

  short4v o0 = { (short)f2bf(v0.x), (short)f2bf(v0.y), (short)f2bf(v0.z), (short)f2bf(v0.w) };
  short4v o1 = { (short)f2bf(v1.x), (short)f2bf(v1.y), (short)f2bf(v1.z), (short)f2bf(v1.w) };
  *(short4v*)(wb + rowoff + t * 4)         = o0;
  *(short4v*)(wb + rowoff + (t + 256) * 4) = o1;
}

template <typename ST>
__device__ __forceinline__ void transpose_body(const ST* __restrict__ in,
                                               bf16_t* __restrict__ out,
                                               int R, int ldin,
                                               long long inB, long long outB,
                                               int xb, int yb, int zb,
                                               int tx, int ty, float* tile)
{
  const size_t zi = (size_t)zb * (size_t)inB;
  const size_t zo = (size_t)zb * (size_t)outB;
  const int c0 = xb * 32, r0 = yb * 32;
#pragma unroll
  for (int k = 0; k < 32; k += 8) {
    ST raw = in[zi + (size_t)(r0 + ty + k) * ldin + (c0 + tx)];
    float v;
    if constexpr (sizeof(ST) == 2) {
      v = __uint_as_float(((unsigned)(unsigned short)raw) << 16);
    } else {
      v = (float)raw;
    }
    tile[(ty + k) * 33 + tx] = v;
  }
  __syncthreads();
#pragma unroll
  for (int k = 0; k < 32; k += 8)
    out[zo + (size_t)(c0 + ty + k) * R + (r0 + tx)] = f2bf(tile[tx * 33 + ty + k]);
}

// ---------------------------------------------------------------------------
// prep: 5 weight transposes (blocks 0..5119) + LN1 rows (blocks 5120..21503)
// ---------------------------------------------------------------------------
__global__ __launch_bounds__(256)
void prep_kernel(const float* __restrict__ Wq, const float* __restrict__ Wk,
                 const float* __restrict__ Wo, const float* __restrict__ W1,
                 const float* __restrict__ W2,
                 bf16_t* __restrict__ WqkT, bf16_t* __restrict__ WoT,
                 bf16_t* __restrict__ W1T, bf16_t* __restrict__ W2T,
                 const float* __restrict__ x, const float* __restrict__ g,
                 const float* __restrict__ b, bf16_t* __restrict__ xn)
{
  __shared__ float smem[32 * 33];
  const int bid = blockIdx.x;
  const int tid = threadIdx.x;
  if (bid < 5120) {
    const int wi = bid >> 10;
    const int rem = bid & 1023;
    const float* src = wi == 0 ? Wq : wi == 1 ? Wk : wi == 2 ? Wo : wi == 3 ? W1 : W2;
    bf16_t* dst = wi == 0 ? WqkT : wi == 1 ? (WqkT + (size_t)DD * DD)
                 : wi == 2 ? WoT : wi == 3 ? W1T : W2T;
    transpose_body<float>(src, dst, DD, DD, 0, 0,
                          rem & 31, rem >> 5, 0, tid & 31, tid >> 5, smem);
  } else {
    ln_body(x, g, b, xn, bid - 5120, tid, smem);
  }
}

__global__ __launch_bounds__(256)
void ln_kernel(const float* __restrict__ x, const float* __restrict__ g,
               const float* __restrict__ b, bf16_t* __restrict__ out)
{
  __shared__ float red[8];
  ln_body(x, g, b, out, blockIdx.x, threadIdx.x, red);
}

// ---------------------------------------------------------------------------
extern "C" void kernel_launch(void* const* d_in, const int* in_sizes, int n_in,
                              void* d_out, int out_size, void* d_ws, size_t ws_size,
                              hipStream_t stream)
{
  const float* x    = (const float*)d_in[0];
  const int*   mask = (const int*)d_in[1];
  const float* ln1g = (const float*)d_in[2];
  const float* ln1b = (const float*)d_in[3];
  const float* Wq   = (const float*)d_in[4];
  const float* bq   = (const float*)d_in[5];
  const float* Wk   = (const float*)d_in[6];
  const float* bk   = (const float*)d_in[7];
  const float* Wo   = (const float*)d_in[8];
  const float* bo   = (const float*)d_in[9];
  const float* ln2g = (const float*)d_in[10];
  const float* ln2b = (const float*)d_in[11];
  const float* W1   = (const float*)d_in[12];
  const float* b1   = (const float*)d_in[13];
  const float* W2   = (const float*)d_in[14];
  const float* b2   = (const float*)d_in[15];

  float* out  = (float*)d_out;                       // (B,S,D) f32, 64MB
  float* wout = out + (size_t)BB * SS * DD;          // (B,S,S) f32, 128MB

  char* ws = (char*)d_ws;
  size_t off = 0;
  auto alloc = [&](size_t bytes) {
    char* p = ws + off; off += (bytes + 255) & ~(size_t)255; return p;
  };
  bf16_t* WqkT = (bf16_t*)alloc((size_t)2 * DD * DD * 2);   // [2048,1024] = WqT ; WkT
  bf16_t* WoT  = (bf16_t*)alloc((size_t)DD * DD * 2);
  bf16_t* W1T  = (bf16_t*)alloc((size_t)DD * DD * 2);
  bf16_t* W2T  = (bf16_t*)alloc((size_t)DD * DD * 2);
  bf16_t* QKb  = (bf16_t*)alloc((size_t)BB * SS * 2 * DD * 2);  // [16384,2048] bf16
  char*   Rwb  = alloc((size_t)64 * 1024 * 1024);               // wbf -> xn2+h
  bf16_t* KWoT = (bf16_t*)alloc((size_t)BB * SS * DD * 2);      // (K@Wo)^T [B,1024,2048]

  bf16_t* wbf = (bf16_t*)Rwb;                      // (B,S,S) bf16, dies after w@KWo
  bf16_t* xn2 = (bf16_t*)Rwb;                      // (B*S,D) bf16 (after wbf dead)
  bf16_t* h   = (bf16_t*)(Rwb + (size_t)32 * 1024 * 1024);  // (B*S,D_FF) bf16

  bf16_t* xn = (bf16_t*)wout;                      // (B*S,D) bf16, dies after QK
  float*  x2 = out;                                // (B*S,D) f32

  const dim3 tb(256);
  const dim3 tg(512);
  const long long SD  = (long long)SS * DD;
  const long long S2  = (long long)SS * SS;
  const long long QKs = (long long)SS * 2 * DD;

  // 1. prep: weights -> transposed bf16 [N][K] (Wq,Wk concatenated) + LN1
  prep_kernel<<<dim3(5120 + BB * SS), tb, 0, stream>>>(
      Wq, Wk, Wo, W1, W2, WqkT, WoT, W1T, W2T, x, ln1g, ln1b, xn);

  // 2. QK = xn @ [Wq|Wk] + [bq|bk]   -- DIAG rep=2 (idempotent)
  gemm256<EPI_BF16, false><<<dim3(512), tg, 0, stream>>>(GemmP{
      xn, WqkT, QKb, bq, bk, nullptr, nullptr,
      64, 8, 1, 8, DD, DD, DD, 2 * DD, 0, 0, 0, 0, 1.0f}, 2);

  // 3. merged scores + KWoT  -- DIAG rep=2 (both idempotent)
  {
    GemmP ps{QKb, QKb + DD, wout, nullptr, nullptr, nullptr, mask,
             8, 8, BB, 8, DD, 2 * DD, 2 * DD, SS, QKs, QKs, S2, SS, 0.03125f};
    GemmP pk{WoT, QKb + DD, KWoT, nullptr, nullptr, nullptr, nullptr,
             4, 8, BB, 8, DD, DD, 2 * DD, SS, 0, QKs, SD, 0, 1.0f};
    gemm_pair<<<dim3(768), tg, 0, stream>>>(ps, 512, pk, 2);
  }

  // 4. softmax rows -> wout (f32, required output) + wbf (bf16)
  softmax_kernel<<<dim3(BB * SS), tb, 0, stream>>>(wout, wbf);

  // 5. x2 = x + w @ KWoT^T + bo  -- DIAG rep=2 (resid = x, not aliased)
  gemm256<EPI_RESID, false><<<dim3(256), tg, 0, stream>>>(GemmP{
      wbf, KWoT, x2, bo, nullptr, x, nullptr,
      8, 4, BB, 4, SS, SS, SS, DD, S2, SD, SD, 0, 1.0f}, 2);

  // 6. xn2 = LN2(x2)
  ln_kernel<<<dim3(BB * SS), tb, 0, stream>>>(x2, ln2g, ln2b, xn2);

  // 7. h = relu(xn2@W1 + b1)  -- DIAG rep=3 (idempotent; 3x to clear fill bar)
  gemm256<EPI_BF16, true><<<dim3(256), tg, 0, stream>>>(GemmP{
      xn2, W1T, h, b1, nullptr, nullptr, nullptr,
      64, 4, 1, 4, DD, DD, DD, DD, 0, 0, 0, 0, 1.0f}, 3);

  // 8. out = x2 + h@W2 + b2  -- rep=1 ONLY (resid x2 aliases out: RMW, not idem.)
  gemm256<EPI_RESID, false><<<dim3(256), tg, 0, stream>>>(GemmP{
      h, W2T, out, b2, nullptr, x2, nullptr,
      64, 4, 1, 4, DD, DD, DD, DD, 0, 0, 0, 0, 1.0f}, 1);
}

// Round 8
// 687.624 us; speedup vs baseline: 2.3585x; 2.3585x over previous
//
#include <hip/hip_runtime.h>
#include <cstdint>
#include <cstddef>

// Problem shape (fixed by reference): B=8, S=2048, D=1024, D_FF=1024
#define BB 8
#define SS 2048
#define DD 1024

typedef unsigned short bf16_t;                                  // raw bf16 bits
typedef __attribute__((ext_vector_type(8))) short bf16x8;       // MFMA A/B frag (4 VGPRs)
typedef __attribute__((ext_vector_type(4))) float f32x4;        // MFMA C/D frag
typedef __attribute__((ext_vector_type(4))) short short4v;

#define EPI_BF16   0   // C = bf16(acc + bias), optional ReLU  (bf16 LDS-bounce store)
#define EPI_SCORES 1   // C = mask ? acc*scale : -1e9  (f32, LDS-bounce coalesced)
#define EPI_RESID  2   // C = acc + bias + resid       (f32, LDS-bounce coalesced RMW)

__device__ __forceinline__ bf16_t f2bf(float f) {
  union { float f; unsigned u; } v; v.f = f;
  unsigned r = v.u + 0x7FFFu + ((v.u >> 16) & 1u);   // RNE
  return (bf16_t)(r >> 16);
}

// async global->LDS, 16B per lane. LDS dst must be wave-uniform base + lane*16.
__device__ __forceinline__ void async_copy16(const void* g, void* l) {
  auto gp = reinterpret_cast<unsigned int __attribute__((address_space(1)))*>(
      reinterpret_cast<uintptr_t>(g));
  auto lp = reinterpret_cast<unsigned int __attribute__((address_space(3)))*>(
      reinterpret_cast<uintptr_t>(l));
  __builtin_amdgcn_global_load_lds(gp, lp, 16, 0, 0);
}

// ---------------------------------------------------------------------------
// GEMM parameter block (by-value kernel arg)
// ---------------------------------------------------------------------------
struct GemmP {
  const bf16_t* A;
  const bf16_t* BT;
  void*         C;
  const float*  bias;   // [<=ldc] or null
  const float*  bias2;  // second-half bias (fused QK) or null
  const float*  resid;  // [Z,M,ldc] f32 (EPI_RESID)
  const int*    mask;   // per-batch mask (EPI_SCORES)
  int Mt, Nt, Z, nchunk;
  int K, lda, ldb, ldc;
  long long sA, sB, sC, sMask;
  float scale;
};

// ---------------------------------------------------------------------------
// 256x256 NT GEMM core: identical to r5 (best-known). See r3-r5 comments.
// r7 diagnostic: ~470 TF, MfmaUtil ~20%, staging-service-bound with ~3x L2
// capacity-miss over-fetch. r8 attacks traffic via nchunk (launch-side only).
// ---------------------------------------------------------------------------
#define MM(i, j, Af, Bf) \
  acc[i][j] = __builtin_amdgcn_mfma_f32_16x16x32_bf16(Af, Bf, acc[i][j], 0, 0, 0)

#define LDA8(D, MH)                                                        \
  { const char* Ah_ = ldsc + (D) * 65536 + (MH) * 16384;                   \
    aF[0] = *(const bf16x8*)(Ah_ + aro +    0 + s0);                       \
    aF[1] = *(const bf16x8*)(Ah_ + aro + 2048 + s0);                       \
    aF[2] = *(const bf16x8*)(Ah_ + aro + 4096 + s0);                       \
    aF[3] = *(const bf16x8*)(Ah_ + aro + 6144 + s0);                       \
    aF[4] = *(const bf16x8*)(Ah_ + aro +    0 + s1);                       \
    aF[5] = *(const bf16x8*)(Ah_ + aro + 2048 + s1);                       \
    aF[6] = *(const bf16x8*)(Ah_ + aro + 4096 + s1);                       \
    aF[7] = *(const bf16x8*)(Ah_ + aro + 6144 + s1); }

#define LDB4(D, NH, BF)                                                    \
  { const char* Bh_ = ldsc + (D) * 65536 + 32768 + (NH) * 16384;           \
    BF[0] = *(const bf16x8*)(Bh_ + bro +    0 + s0);                       \
    BF[1] = *(const bf16x8*)(Bh_ + bro + 2048 + s0);                       \
    BF[2] = *(const bf16x8*)(Bh_ + bro +    0 + s1);                       \
    BF[3] = *(const bf16x8*)(Bh_ + bro + 2048 + s1); }

#define MFMA16(MH, NH, BF)                                                 \
  __builtin_amdgcn_s_setprio(1);                                           \
  MM((MH)*4+0,(NH)*2+0,aF[0],BF[0]); MM((MH)*4+1,(NH)*2+0,aF[1],BF[0]);    \
  MM((MH)*4+2,(NH)*2+0,aF[2],BF[0]); MM((MH)*4+3,(NH)*2+0,aF[3],BF[0]);    \
  MM((MH)*4+0,(NH)*2+1,aF[0],BF[1]); MM((MH)*4+1,(NH)*2+1,aF[1],BF[1]);    \
  MM((MH)*4+2,(NH)*2+1,aF[2],BF[1]); MM((MH)*4+3,(NH)*2+1,aF[3],BF[1]);    \
  MM((MH)*4+0,(NH)*2+0,aF[4],BF[2]); MM((MH)*4+1,(NH)*2+0,aF[5],BF[2]);    \
  MM((MH)*4+2,(NH)*2+0,aF[6],BF[2]); MM((MH)*4+3,(NH)*2+0,aF[7],BF[2]);    \
  MM((MH)*4+0,(NH)*2+1,aF[4],BF[3]); MM((MH)*4+1,(NH)*2+1,aF[5],BF[3]);    \
  MM((MH)*4+2,(NH)*2+1,aF[6],BF[3]); MM((MH)*4+3,(NH)*2+1,aF[7],BF[3]);    \
  __builtin_amdgcn_s_setprio(0);

template <int EPI, bool RELU>
__device__ __forceinline__ void gemm_core(const GemmP p, int b, char* ldsc)
{
  // ---- XCD swizzle: contiguous idx chunk per XCD ----
  const int Cchunk = (p.Z * p.Mt * p.Nt) >> 3;     // tile count divisible by 8
  int idx = (b & 7) * Cchunk + (b >> 3);
  const int per_z = p.Mt * p.Nt;
  const int z = idx / per_z;  idx -= z * per_z;
  const int per_nc = p.Mt * p.nchunk;
  const int nc = idx / per_nc; idx -= nc * per_nc;
  const int mt = idx / p.nchunk;
  const int nin = idx - mt * p.nchunk;
  const int m0 = mt * 256;
  const int n0 = (nc * p.nchunk + nin) * 256;

  const int tid  = threadIdx.x;
  const int wave = tid >> 6;
  const int lane = tid & 63;
  const int wr   = wave >> 2, wc = wave & 3;       // 2 x 4 wave grid
  const int lr   = lane & 15, quad = lane >> 4;

  const bf16_t* Ab = p.A  + (size_t)z * (size_t)p.sA;
  const bf16_t* Bb = p.BT + (size_t)z * (size_t)p.sB;

  f32x4 acc[8][4];
#pragma unroll
  for (int i = 0; i < 8; ++i)
#pragma unroll
    for (int j = 0; j < 4; ++j)
#pragma unroll
      for (int r = 0; r < 4; ++r) acc[i][j][r] = 0.0f;

  // staging geometry, hoisted. Slot p holds logical k-chunk p^(row&7).
  const bf16_t* gA[2]; const bf16_t* gB[2]; char* lA[2]; char* lB[2];
#pragma unroll
  for (int u = 0; u < 2; ++u) {
    const int c = tid + u * 512;
    const int rl = c >> 3;
    const int csw = (((c & 7) ^ (rl & 7)) << 3);                 // swizzled k-elems
    const int rowA = ((rl & 64) << 1) + (rl & 63);               // rows 0..63,128..191
    const int rowB = ((rl & 96) << 1) + (rl & 31);
    gA[u] = Ab + (size_t)(m0 + rowA) * p.lda + csw;
    gB[u] = Bb + (size_t)(n0 + rowB) * p.ldb + csw;
    lA[u] = ldsc + c * 16;
    lB[u] = ldsc + 32768 + c * 16;
  }
  const int ldA64 = p.lda << 6, ldB64 = p.ldb << 5;

  auto stageA = [&](int d, int mh, int kt) {
    const int go = mh * ldA64 + kt;
    const int lo = d * 65536 + mh * 16384;
#pragma unroll
    for (int u = 0; u < 2; ++u) async_copy16(gA[u] + go, lA[u] + lo);
  };
  auto stageB = [&](int d, int nh, int kt) {
    const int go = nh * ldB64 + kt;
    const int lo = d * 65536 + nh * 16384;
#pragma unroll
    for (int u = 0; u < 2; ++u) async_copy16(gB[u] + go, lB[u] + lo);
  };

  // ds_read addressing: logical slot s = ks*4+quad; physical = s^(lr&7)
  const int s0  = ((quad ^ (lr & 7)) << 4);
  const int s1  = s0 ^ 64;
  const int aro = (wr * 64 + lr) << 7;
  const int bro = (wc * 32 + lr) << 7;

  bf16x8 aF[8];
  bf16x8 bF0[4], bF1[4];

  const int NT = p.K >> 6;

  // ---- prologue ----
  stageA(0, 0, 0); stageA(0, 1, 0); stageB(0, 0, 0); stageB(0, 1, 0);
  if (NT > 1) {
    stageA(1, 0, 64); stageB(1, 0, 64);
    asm volatile("s_waitcnt vmcnt(4)" ::: "memory");
  } else {
    asm volatile("s_waitcnt vmcnt(0)" ::: "memory");
  }
  __builtin_amdgcn_s_barrier();

#pragma unroll 2
  for (int t = 0; t < NT; ++t) {
    const int d  = t & 1;
    const int k1 = (t + 1) << 6;
    const int k2 = (t + 2) << 6;

    LDA8(d, 0); LDB4(d, 0, bF0);
    if (t + 1 < NT) stageA(d ^ 1, 1, k1);
    __builtin_amdgcn_s_barrier();
    MFMA16(0, 0, bF0);

    LDB4(d, 1, bF1);
    if (t + 1 < NT) stageB(d ^ 1, 1, k1);
    __builtin_amdgcn_s_barrier();
    MFMA16(0, 1, bF1);

    LDA8(d, 1);
    if (t + 2 < NT) stageA(d, 0, k2);
    __builtin_amdgcn_s_barrier();
    MFMA16(1, 1, bF1);

    if (t + 2 < NT) {
      stageB(d, 0, k2);
      asm volatile("s_waitcnt vmcnt(4)" ::: "memory");
    } else {
      asm volatile("s_waitcnt vmcnt(0)" ::: "memory");
    }
    __builtin_amdgcn_s_barrier();
    MFMA16(1, 0, bF0);
  }

  // ---- epilogue ----  (C/D layout: col = lane&15, row = quad*4 + r)
  if constexpr (EPI == EPI_BF16) {
    char* Wb = ldsc + wave * 16384;
#pragma unroll
    for (int i = 0; i < 8; ++i) {
      const int mb = (i >> 2) * 64 + (i & 3) * 16 + quad * 4;     // + r
#pragma unroll
      for (int j = 0; j < 4; ++j) {
        const int nl = (j >> 1) * 32 + (j & 1) * 16 + lr;         // 0..63
        const int gn = n0 + wc * 64 + nl;
        const float bv = (p.bias2 && gn >= 1024) ? p.bias2[gn - 1024]
                       : (p.bias ? p.bias[gn] : 0.0f);
#pragma unroll
        for (int r = 0; r < 4; ++r) {
          float v = acc[i][j][r] + bv;
          if (RELU) v = fmaxf(v, 0.0f);
          const int m = mb + r;
          const int nb = nl * 2;
          const int phys = (m << 7) + (((nb & ~15) ^ ((m & 7) << 4)) | (nb & 15));
          *(bf16_t*)(Wb + phys) = f2bf(v);
        }
      }
    }
    asm volatile("s_waitcnt lgkmcnt(0)" ::: "memory");
    bf16_t* Cb = (bf16_t*)p.C + (size_t)z * (size_t)p.sC
               + (size_t)(m0 + wr * 128) * p.ldc + (n0 + wc * 64);
#pragma unroll
    for (int q = 0; q < 16; ++q) {
      const int m = q * 8 + (lane >> 3);
      const int c = lane & 7;
      const bf16x8 vv = *(const bf16x8*)(Wb + (m << 7) + (((c ^ (m & 7)) << 4)));
      *(bf16x8*)(Cb + (size_t)m * p.ldc + c * 8) = vv;
    }
  } else {
    char* Wb = ldsc + wave * 16384;
#pragma unroll
    for (int hh = 0; hh < 2; ++hh) {
#pragma unroll
      for (int ii = 0; ii < 4; ++ii) {
        const int i = hh * 4 + ii;
        const int ml = ii * 16 + quad * 4;                        // + r
#pragma unroll
        for (int j = 0; j < 4; ++j) {
          const int nl = (j >> 1) * 32 + (j & 1) * 16 + lr;       // 0..63
          const int gn = n0 + wc * 64 + nl;
          float addv = 0.0f; int mk = 1;
          if constexpr (EPI == EPI_RESID) addv = p.bias ? p.bias[gn] : 0.0f;
          if constexpr (EPI == EPI_SCORES)
            mk = p.mask[(size_t)z * (size_t)p.sMask + gn];
#pragma unroll
          for (int r = 0; r < 4; ++r) {
            const int m = ml + r;
            float v = acc[i][j][r];
            if constexpr (EPI == EPI_SCORES) v = mk ? v * p.scale : -1e9f;
            else v += addv;
            const int nph = nl ^ (((m >> 2) & 3) << 2);
            *(float*)(Wb + m * 256 + nph * 4) = v;
          }
        }
      }
      asm volatile("s_waitcnt lgkmcnt(0)" ::: "memory");
      const int mb = m0 + wr * 128 + hh * 64;
      const int gn0 = n0 + wc * 64 + lr * 4;
#pragma unroll
      for (int q = 0; q < 16; ++q) {
        const int m = q * 4 + quad;
        const int nph = (lr * 4) ^ (((m >> 2) & 3) << 2);
        f32x4 v = *(const f32x4*)(Wb + m * 256 + nph * 4);
        const size_t off = (size_t)z * (size_t)p.sC
                         + (size_t)(mb + m) * p.ldc + gn0;
        if constexpr (EPI == EPI_RESID) {
          const f32x4 rv = *(const f32x4*)(p.resid + off);
          v = v + rv;
        }
        *(f32x4*)((float*)p.C + off) = v;
      }
      if (hh == 0) { asm volatile("s_waitcnt lgkmcnt(0)" ::: "memory"); }
    }
  }
}

template <int EPI, bool RELU>
__global__ __launch_bounds__(512, 2)
void gemm256(GemmP p)
{
  __shared__ __align__(16) char lds_[131072];
  gemm_core<EPI, RELU>(p, blockIdx.x, lds_);
}

// merged launch: blocks [0,n1) run EPI_SCORES on p1; [n1,...) EPI_BF16 on p2.
__global__ __launch_bounds__(512, 2)
void gemm_pair(GemmP p1, int n1, GemmP p2)
{
  __shared__ __align__(16) char lds_[131072];
  if ((int)blockIdx.x < n1) gemm_core<EPI_SCORES, false>(p1, blockIdx.x, lds_);
  else                      gemm_core<EPI_BF16,   false>(p2, blockIdx.x - n1, lds_);
}

// ---------------------------------------------------------------------------
// Shared device bodies: LayerNorm row, softmax row, 32x32 tile transpose.
// ---------------------------------------------------------------------------
__device__ __forceinline__ void ln_body(const float* __restrict__ x,
                                        const float* __restrict__ g,
                                        const float* __restrict__ b,
                                        bf16_t* __restrict__ out,
                                        int row, int t, float* red)
{
  const int wave = t >> 6, lane = t & 63;
  const float4 v = ((const float4*)(x + (size_t)row * DD))[t];

  float s = v.x + v.y + v.z + v.w;
#pragma unroll
  for (int o = 32; o > 0; o >>= 1) s += __shfl_down(s, o);
  if (lane == 0) red[wave] = s;
  __syncthreads();
  const float mu = (red[0] + red[1] + red[2] + red[3]) * (1.0f / DD);

  const float d0 = v.x - mu, d1 = v.y - mu, d2 = v.z - mu, d3 = v.w - mu;
  float ss = d0 * d0 + d1 * d1 + d2 * d2 + d3 * d3;
#pragma unroll
  for (int o = 32; o > 0; o >>= 1) ss += __shfl_down(ss, o);
  if (lane == 0) red[4 + wave] = ss;
  __syncthreads();
  const float var = (red[4] + red[5] + red[6] + red[7]) * (1.0f / DD);
  const float rs  = rsqrtf(var + 1e-5f);

  const float4 gg = ((const float4*)g)[t];
  const float4 bb = ((const float4*)b)[t];
  short4v o;
  o.x = (short)f2bf(d0 * rs * gg.x + bb.x);
  o.y = (short)f2bf(d1 * rs * gg.y + bb.y);
  o.z = (short)f2bf(d2 * rs * gg.z + bb.z);
  o.w = (short)f2bf(d3 * rs * gg.w + bb.w);
  *(short4v*)(out + (size_t)row * DD + t * 4) = o;
}

__global__ __launch_bounds__(256)
void softmax_kernel(float* __restrict__ w, bf16_t* __restrict__ wb)
{
  __shared__ float red[8];
  const size_t rowoff = (size_t)blockIdx.x * SS;
  float* p = w + rowoff;
  const int t = threadIdx.x;
  const int wave = t >> 6, lane = t & 63;
  float4 v0 = ((float4*)p)[t];
  float4 v1 = ((float4*)p)[t + 256];

  float m = fmaxf(fmaxf(fmaxf(v0.x, v0.y), fmaxf(v0.z, v0.w)),
                  fmaxf(fmaxf(v1.x, v1.y), fmaxf(v1.z, v1.w)));
#pragma unroll
  for (int o = 32; o > 0; o >>= 1) m = fmaxf(m, __shfl_down(m, o));
  if (lane == 0) red[wave] = m;
  __syncthreads();
  m = fmaxf(fmaxf(red[0], red[1]), fmaxf(red[2], red[3]));

  v0.x = __expf(v0.x - m); v0.y = __expf(v0.y - m);
  v0.z = __expf(v0.z - m); v0.w = __expf(v0.w - m);
  v1.x = __expf(v1.x - m); v1.y = __expf(v1.y - m);
  v1.z = __expf(v1.z - m); v1.w = __expf(v1.w - m);

  float s = v0.x + v0.y + v0.z + v0.w + v1.x + v1.y + v1.z + v1.w;
#pragma unroll
  for (int o = 32; o > 0; o >>= 1) s += __shfl_down(s, o);
  if (lane == 0) red[4 + wave] = s;
  __syncthreads();
  const float inv = 1.0f / (red[4] + red[5] + red[6] + red[7]);

  v0.x *= inv; v0.y *= inv; v0.z *= inv; v0.w *= inv;
  v1.x *= inv; v1.y *= inv; v1.z *= inv; v1.w *= inv;
  ((float4*)p)[t] = v0;
  ((float4*)p)[t + 256] = v1;

  short4v o0 = { (short)f2bf(v0.x), (short)f2bf(v0.y), (short)f2bf(v0.z), (short)f2bf(v0.w) };
  short4v o1 = { (short)f2bf(v1.x), (short)f2bf(v1.y), (short)f2bf(v1.z), (short)f2bf(v1.w) };
  *(short4v*)(wb + rowoff + t * 4)         = o0;
  *(short4v*)(wb + rowoff + (t + 256) * 4) = o1;
}

template <typename ST>
__device__ __forceinline__ void transpose_body(const ST* __restrict__ in,
                                               bf16_t* __restrict__ out,
                                               int R, int ldin,
                                               long long inB, long long outB,
                                               int xb, int yb, int zb,
                                               int tx, int ty, float* tile)
{
  const size_t zi = (size_t)zb * (size_t)inB;
  const size_t zo = (size_t)zb * (size_t)outB;
  const int c0 = xb * 32, r0 = yb * 32;
#pragma unroll
  for (int k = 0; k < 32; k += 8) {
    ST raw = in[zi + (size_t)(r0 + ty + k) * ldin + (c0 + tx)];
    float v;
    if constexpr (sizeof(ST) == 2) {
      v = __uint_as_float(((unsigned)(unsigned short)raw) << 16);
    } else {
      v = (float)raw;
    }
    tile[(ty + k) * 33 + tx] = v;
  }
  __syncthreads();
#pragma unroll
  for (int k = 0; k < 32; k += 8)
    out[zo + (size_t)(c0 + ty + k) * R + (r0 + tx)] = f2bf(tile[tx * 33 + ty + k]);
}

// ---------------------------------------------------------------------------
// prep: 5 weight transposes (blocks 0..5119) + LN1 rows (blocks 5120..21503)
// ---------------------------------------------------------------------------
__global__ __launch_bounds__(256)
void prep_kernel(const float* __restrict__ Wq, const float* __restrict__ Wk,
                 const float* __restrict__ Wo, const float* __restrict__ W1,
                 const float* __restrict__ W2,
                 bf16_t* __restrict__ WqkT, bf16_t* __restrict__ WoT,
                 bf16_t* __restrict__ W1T, bf16_t* __restrict__ W2T,
                 const float* __restrict__ x, const float* __restrict__ g,
                 const float* __restrict__ b, bf16_t* __restrict__ xn)
{
  __shared__ float smem[32 * 33];
  const int bid = blockIdx.x;
  const int tid = threadIdx.x;
  if (bid < 5120) {
    const int wi = bid >> 10;
    const int rem = bid & 1023;
    const float* src = wi == 0 ? Wq : wi == 1 ? Wk : wi == 2 ? Wo : wi == 3 ? W1 : W2;
    bf16_t* dst = wi == 0 ? WqkT : wi == 1 ? (WqkT + (size_t)DD * DD)
                 : wi == 2 ? WoT : wi == 3 ? W1T : W2T;
    transpose_body<float>(src, dst, DD, DD, 0, 0,
                          rem & 31, rem >> 5, 0, tid & 31, tid >> 5, smem);
  } else {
    ln_body(x, g, b, xn, bid - 5120, tid, smem);
  }
}

__global__ __launch_bounds__(256)
void ln_kernel(const float* __restrict__ x, const float* __restrict__ g,
               const float* __restrict__ b, bf16_t* __restrict__ out)
{
  __shared__ float red[8];
  ln_body(x, g, b, out, blockIdx.x, threadIdx.x, red);
}

// ---------------------------------------------------------------------------
extern "C" void kernel_launch(void* const* d_in, const int* in_sizes, int n_in,
                              void* d_out, int out_size, void* d_ws, size_t ws_size,
                              hipStream_t stream)
{
  const float* x    = (const float*)d_in[0];
  const int*   mask = (const int*)d_in[1];
  const float* ln1g = (const float*)d_in[2];
  const float* ln1b = (const float*)d_in[3];
  const float* Wq   = (const float*)d_in[4];
  const float* bq   = (const float*)d_in[5];
  const float* Wk   = (const float*)d_in[6];
  const float* bk   = (const float*)d_in[7];
  const float* Wo   = (const float*)d_in[8];
  const float* bo   = (const float*)d_in[9];
  const float* ln2g = (const float*)d_in[10];
  const float* ln2b = (const float*)d_in[11];
  const float* W1   = (const float*)d_in[12];
  const float* b1   = (const float*)d_in[13];
  const float* W2   = (const float*)d_in[14];
  const float* b2   = (const float*)d_in[15];

  float* out  = (float*)d_out;                       // (B,S,D) f32, 64MB
  float* wout = out + (size_t)BB * SS * DD;          // (B,S,S) f32, 128MB

  char* ws = (char*)d_ws;
  size_t off = 0;
  auto alloc = [&](size_t bytes) {
    char* p = ws + off; off += (bytes + 255) & ~(size_t)255; return p;
  };
  bf16_t* WqkT = (bf16_t*)alloc((size_t)2 * DD * DD * 2);   // [2048,1024] = WqT ; WkT
  bf16_t* WoT  = (bf16_t*)alloc((size_t)DD * DD * 2);
  bf16_t* W1T  = (bf16_t*)alloc((size_t)DD * DD * 2);
  bf16_t* W2T  = (bf16_t*)alloc((size_t)DD * DD * 2);
  bf16_t* QKb  = (bf16_t*)alloc((size_t)BB * SS * 2 * DD * 2);  // [16384,2048] bf16
  char*   Rwb  = alloc((size_t)64 * 1024 * 1024);               // wbf -> xn2+h
  bf16_t* KWoT = (bf16_t*)alloc((size_t)BB * SS * DD * 2);      // (K@Wo)^T [B,1024,2048]

  bf16_t* wbf = (bf16_t*)Rwb;                      // (B,S,S) bf16, dies after w@KWo
  bf16_t* xn2 = (bf16_t*)Rwb;                      // (B*S,D) bf16 (after wbf dead)
  bf16_t* h   = (bf16_t*)(Rwb + (size_t)32 * 1024 * 1024);  // (B*S,D_FF) bf16

  bf16_t* xn = (bf16_t*)wout;                      // (B*S,D) bf16, dies after QK
  float*  x2 = out;                                // (B*S,D) f32

  const dim3 tb(256);
  const dim3 tg(512);
  const long long SD  = (long long)SS * DD;
  const long long S2  = (long long)SS * SS;
  const long long QKs = (long long)SS * 2 * DD;

  // 1. prep: weights -> transposed bf16 [N][K] (Wq,Wk concatenated) + LN1
  prep_kernel<<<dim3(5120 + BB * SS), tb, 0, stream>>>(
      Wq, Wk, Wo, W1, W2, WqkT, WoT, W1T, W2T, x, ln1g, ln1b, xn);

  // 2. QK = xn @ [Wq|Wk] + [bq|bk]   (bf16, [16384,2048])
  //    B total = 4MB shared by all XCDs -> L2-resident; nchunk stays 8.
  gemm256<EPI_BF16, false><<<dim3(512), tg, 0, stream>>>(GemmP{
      xn, WqkT, QKb, bq, bk, nullptr, nullptr,
      64, 8, 1, 8, DD, DD, DD, 2 * DD, 0, 0, 0, 0, 1.0f});

  // 3. merged: scores (blocks 0..511) + KWoT (512..767)
  //    nchunk 8->4: per-XCD B-working-set 4MB->2MB (was == full L2 -> thrash;
  //    r7 measured 3x read over-fetch). A re-read x2 (32MB) << B thrash saved.
  {
    GemmP ps{QKb, QKb + DD, wout, nullptr, nullptr, nullptr, mask,
             8, 8, BB, 4, DD, 2 * DD, 2 * DD, SS, QKs, QKs, S2, SS, 0.03125f};
    GemmP pk{WoT, QKb + DD, KWoT, nullptr, nullptr, nullptr, nullptr,
             4, 8, BB, 4, DD, DD, 2 * DD, SS, 0, QKs, SD, 0, 1.0f};
    gemm_pair<<<dim3(768), tg, 0, stream>>>(ps, 512, pk);
  }

  // 4. softmax rows -> wout (f32, required output) + wbf (bf16)
  softmax_kernel<<<dim3(BB * SS), tb, 0, stream>>>(wout, wbf);

  // 5. x2 = x + w @ KWoT^T + bo.  nchunk 4->2: B-chunk 4MB->2MB (K=2048 panels
  //    are 1MB each; 4-panel chunk == full L2 -> thrash).
  gemm256<EPI_RESID, false><<<dim3(256), tg, 0, stream>>>(GemmP{
      wbf, KWoT, x2, bo, nullptr, x, nullptr,
      8, 4, BB, 2, SS, SS, SS, DD, S2, SD, SD, 0, 1.0f});

  // 6. xn2 = LN2(x2)
  ln_kernel<<<dim3(BB * SS), tb, 0, stream>>>(x2, ln2g, ln2b, xn2);

  // 7. h = relu(xn2@W1 + b1)  (bf16; B = 2MB weight, L2-resident)
  gemm256<EPI_BF16, true><<<dim3(256), tg, 0, stream>>>(GemmP{
      xn2, W1T, h, b1, nullptr, nullptr, nullptr,
      64, 4, 1, 4, DD, DD, DD, DD, 0, 0, 0, 0, 1.0f});

  // 8. out = x2 + h@W2 + b2  (f32, elementwise RMW of out region)
  gemm256<EPI_RESID, false><<<dim3(256), tg, 0, stream>>>(GemmP{
      h, W2T, out, b2, nullptr, x2, nullptr,
      64, 4, 1, 4, DD, DD, DD, DD, 0, 0, 0, 0, 1.0f});
}

// Round 10
// 667.001 us; speedup vs baseline: 2.4315x; 1.0309x over previous
//
#include <hip/hip_runtime.h>
#include <cstdint>
#include <cstddef>

// Problem shape (fixed by reference): B=8, S=2048, D=1024, D_FF=1024
#define BB 8
#define SS 2048
#define DD 1024

typedef unsigned short bf16_t;                                  // raw bf16 bits
typedef __attribute__((ext_vector_type(8))) short bf16x8;       // MFMA A/B frag (4 VGPRs)
typedef __attribute__((ext_vector_type(4))) float f32x4;        // MFMA C/D frag
typedef __attribute__((ext_vector_type(4))) short short4v;

#define EPI_BF16   0   // C = bf16(acc + bias), optional ReLU  (bf16 LDS-bounce store)
#define EPI_SCORES 1   // C = mask ? acc*scale : -1e9  (f32, LDS-bounce coalesced)
#define EPI_RESID  2   // C = acc + bias + resid       (f32, LDS-bounce coalesced RMW)

__device__ __forceinline__ bf16_t f2bf(float f) {
  union { float f; unsigned u; } v; v.f = f;
  unsigned r = v.u + 0x7FFFu + ((v.u >> 16) & 1u);   // RNE
  return (bf16_t)(r >> 16);
}

// async global->LDS, 16B per lane. LDS dst must be wave-uniform base + lane*16.
__device__ __forceinline__ void async_copy16(const void* g, void* l) {
  auto gp = reinterpret_cast<unsigned int __attribute__((address_space(1)))*>(
      reinterpret_cast<uintptr_t>(g));
  auto lp = reinterpret_cast<unsigned int __attribute__((address_space(3)))*>(
      reinterpret_cast<uintptr_t>(l));
  __builtin_amdgcn_global_load_lds(gp, lp, 16, 0, 0);
}

// ---------------------------------------------------------------------------
// GEMM parameter block (by-value kernel arg)
// ---------------------------------------------------------------------------
struct GemmP {
  const bf16_t* A;
  const bf16_t* BT;
  void*         C;
  const float*  bias;   // [<=ldc] or null
  const float*  bias2;  // second-half bias (fused QK) or null
  const float*  resid;  // [Z,M,ldc] f32 (EPI_RESID)
  const int*    mask;   // per-batch mask (EPI_SCORES)
  int Mt, Nt, Z, nchunk;
  int K, lda, ldb, ldc;
  long long sA, sB, sC, sMask;
  float scale;
};

// ---------------------------------------------------------------------------
// 256x256 NT GEMM core. r9 intent, race-fixed: smooth LDS-port window load
// 12/4/8/0 -> 8/4/8/4 by pre-reading next tile's B0 in w4's MFMA window.
// RACE FIX vs r9: vmcnt is PER-WAVE — the pre-read must sit AFTER the w4
// barrier (all waves past vmcnt(4) => tile t+1 resident for every wave's
// loads), not after only this wave's vmcnt. Overwrite of that region happens
// at w4 of t+1, reachable only after BAR1-of-t+1, which this wave passes only
// after the lgkm-forced bF0=bF0n copy -> read completes first.
// nchunk = r5 values (r8 A/B: smaller nchunk cut FETCH 3x but raised time).
// ---------------------------------------------------------------------------
#define MM(i, j, Af, Bf) \
  acc[i][j] = __builtin_amdgcn_mfma_f32_16x16x32_bf16(Af, Bf, acc[i][j], 0, 0, 0)

#define LDA8(D, MH)                                                        \
  { const char* Ah_ = ldsc + (D) * 65536 + (MH) * 16384;                   \
    aF[0] = *(const bf16x8*)(Ah_ + aro +    0 + s0);                       \
    aF[1] = *(const bf16x8*)(Ah_ + aro + 2048 + s0);                       \
    aF[2] = *(const bf16x8*)(Ah_ + aro + 4096 + s0);                       \
    aF[3] = *(const bf16x8*)(Ah_ + aro + 6144 + s0);                       \
    aF[4] = *(const bf16x8*)(Ah_ + aro +    0 + s1);                       \
    aF[5] = *(const bf16x8*)(Ah_ + aro + 2048 + s1);                       \
    aF[6] = *(const bf16x8*)(Ah_ + aro + 4096 + s1);                       \
    aF[7] = *(const bf16x8*)(Ah_ + aro + 6144 + s1); }

#define LDB4(D, NH, BF)                                                    \
  { const char* Bh_ = ldsc + (D) * 65536 + 32768 + (NH) * 16384;           \
    BF[0] = *(const bf16x8*)(Bh_ + bro +    0 + s0);                       \
    BF[1] = *(const bf16x8*)(Bh_ + bro + 2048 + s0);                       \
    BF[2] = *(const bf16x8*)(Bh_ + bro +    0 + s1);                       \
    BF[3] = *(const bf16x8*)(Bh_ + bro + 2048 + s1); }

#define MFMA16(MH, NH, BF)                                                 \
  __builtin_amdgcn_s_setprio(1);                                           \
  MM((MH)*4+0,(NH)*2+0,aF[0],BF[0]); MM((MH)*4+1,(NH)*2+0,aF[1],BF[0]);    \
  MM((MH)*4+2,(NH)*2+0,aF[2],BF[0]); MM((MH)*4+3,(NH)*2+0,aF[3],BF[0]);    \
  MM((MH)*4+0,(NH)*2+1,aF[0],BF[1]); MM((MH)*4+1,(NH)*2+1,aF[1],BF[1]);    \
  MM((MH)*4+2,(NH)*2+1,aF[2],BF[1]); MM((MH)*4+3,(NH)*2+1,aF[3],BF[1]);    \
  MM((MH)*4+0,(NH)*2+0,aF[4],BF[2]); MM((MH)*4+1,(NH)*2+0,aF[5],BF[2]);    \
  MM((MH)*4+2,(NH)*2+0,aF[6],BF[2]); MM((MH)*4+3,(NH)*2+0,aF[7],BF[2]);    \
  MM((MH)*4+0,(NH)*2+1,aF[4],BF[3]); MM((MH)*4+1,(NH)*2+1,aF[5],BF[3]);    \
  MM((MH)*4+2,(NH)*2+1,aF[6],BF[3]); MM((MH)*4+3,(NH)*2+1,aF[7],BF[3]);    \
  __builtin_amdgcn_s_setprio(0);

template <int EPI, bool RELU>
__device__ __forceinline__ void gemm_core(const GemmP p, int b, char* ldsc)
{
  // ---- XCD swizzle: contiguous idx chunk per XCD ----
  const int Cchunk = (p.Z * p.Mt * p.Nt) >> 3;     // tile count divisible by 8
  int idx = (b & 7) * Cchunk + (b >> 3);
  const int per_z = p.Mt * p.Nt;
  const int z = idx / per_z;  idx -= z * per_z;
  const int per_nc = p.Mt * p.nchunk;
  const int nc = idx / per_nc; idx -= nc * per_nc;
  const int mt = idx / p.nchunk;
  const int nin = idx - mt * p.nchunk;
  const int m0 = mt * 256;
  const int n0 = (nc * p.nchunk + nin) * 256;

  const int tid  = threadIdx.x;
  const int wave = tid >> 6;
  const int lane = tid & 63;
  const int wr   = wave >> 2, wc = wave & 3;       // 2 x 4 wave grid
  const int lr   = lane & 15, quad = lane >> 4;

  const bf16_t* Ab = p.A  + (size_t)z * (size_t)p.sA;
  const bf16_t* Bb = p.BT + (size_t)z * (size_t)p.sB;

  f32x4 acc[8][4];
#pragma unroll
  for (int i = 0; i < 8; ++i)
#pragma unroll
    for (int j = 0; j < 4; ++j)
#pragma unroll
      for (int r = 0; r < 4; ++r) acc[i][j][r] = 0.0f;

  // staging geometry, hoisted. Slot p holds logical k-chunk p^(row&7).
  const bf16_t* gA[2]; const bf16_t* gB[2]; char* lA[2]; char* lB[2];
#pragma unroll
  for (int u = 0; u < 2; ++u) {
    const int c = tid + u * 512;
    const int rl = c >> 3;
    const int csw = (((c & 7) ^ (rl & 7)) << 3);                 // swizzled k-elems
    const int rowA = ((rl & 64) << 1) + (rl & 63);               // rows 0..63,128..191
    const int rowB = ((rl & 96) << 1) + (rl & 31);
    gA[u] = Ab + (size_t)(m0 + rowA) * p.lda + csw;
    gB[u] = Bb + (size_t)(n0 + rowB) * p.ldb + csw;
    lA[u] = ldsc + c * 16;
    lB[u] = ldsc + 32768 + c * 16;
  }
  const int ldA64 = p.lda << 6, ldB64 = p.ldb << 5;

  auto stageA = [&](int d, int mh, int kt) {
    const int go = mh * ldA64 + kt;
    const int lo = d * 65536 + mh * 16384;
#pragma unroll
    for (int u = 0; u < 2; ++u) async_copy16(gA[u] + go, lA[u] + lo);
  };
  auto stageB = [&](int d, int nh, int kt) {
    const int go = nh * ldB64 + kt;
    const int lo = d * 65536 + nh * 16384;
#pragma unroll
    for (int u = 0; u < 2; ++u) async_copy16(gB[u] + go, lB[u] + lo);
  };

  // ds_read addressing: logical slot s = ks*4+quad; physical = s^(lr&7)
  const int s0  = ((quad ^ (lr & 7)) << 4);
  const int s1  = s0 ^ 64;
  const int aro = (wr * 64 + lr) << 7;
  const int bro = (wc * 32 + lr) << 7;

  bf16x8 aF[8];
  bf16x8 bF0[4], bF0n[4], bF1[4];

  const int NT = p.K >> 6;

  // ---- prologue: tile0 (4 halves) + tile1 (A0, B0) ----
  stageA(0, 0, 0); stageA(0, 1, 0); stageB(0, 0, 0); stageB(0, 1, 0);
  if (NT > 1) {
    stageA(1, 0, 64); stageB(1, 0, 64);
    asm volatile("s_waitcnt vmcnt(4)" ::: "memory");   // tile0 resident (this wave)
  } else {
    asm volatile("s_waitcnt vmcnt(0)" ::: "memory");
  }
  __builtin_amdgcn_s_barrier();          // ALL waves past vmcnt => tile0 resident
  LDB4(0, 0, bF0);                       // tile0 B0 pre-read (post-barrier: safe)

#pragma unroll 2
  for (int t = 0; t < NT; ++t) {
    const int d  = t & 1;
    const int k1 = (t + 1) << 6;
    const int k2 = (t + 2) << 6;

    // w1: quadrant (0,0) — A0 fresh (8 reads); B0 pre-read last window
    LDA8(d, 0);
    if (t + 1 < NT) stageA(d ^ 1, 1, k1);
    __builtin_amdgcn_s_barrier();
    MFMA16(0, 0, bF0);

    // w2: quadrant (0,1) — B1 fresh (4 reads), reuse A0
    LDB4(d, 1, bF1);
    if (t + 1 < NT) stageB(d ^ 1, 1, k1);
    __builtin_amdgcn_s_barrier();
    MFMA16(0, 1, bF1);

    // w3: quadrant (1,1) — A1 fresh (8 reads), reuse B1
    LDA8(d, 1);
    if (t + 2 < NT) stageA(d, 0, k2);
    __builtin_amdgcn_s_barrier();
    MFMA16(1, 1, bF1);

    // w4: quadrant (1,0) — reuse A1+B0; stage t+2.B0; counted wait; barrier;
    // THEN pre-read next tile's B0 inside the MFMA window (post-barrier =>
    // every wave's tile-t+1 loads drained; per-wave vmcnt alone is NOT enough).
    if (t + 2 < NT) {
      stageB(d, 0, k2);
      asm volatile("s_waitcnt vmcnt(4)" ::: "memory");
    } else {
      asm volatile("s_waitcnt vmcnt(0)" ::: "memory");
    }
    __builtin_amdgcn_s_barrier();
    if (t + 1 < NT) LDB4(d ^ 1, 0, bF0n);
    MFMA16(1, 0, bF0);
    if (t + 1 < NT) {
#pragma unroll
      for (int q = 0; q < 4; ++q) bF0[q] = bF0n[q];   // lgkm wait lands here
    }
  }

  // ---- epilogue ----  (C/D layout: col = lane&15, row = quad*4 + r)
  if constexpr (EPI == EPI_BF16) {
    char* Wb = ldsc + wave * 16384;
#pragma unroll
    for (int i = 0; i < 8; ++i) {
      const int mb = (i >> 2) * 64 + (i & 3) * 16 + quad * 4;     // + r
#pragma unroll
      for (int j = 0; j < 4; ++j) {
        const int nl = (j >> 1) * 32 + (j & 1) * 16 + lr;         // 0..63
        const int gn = n0 + wc * 64 + nl;
        const float bv = (p.bias2 && gn >= 1024) ? p.bias2[gn - 1024]
                       : (p.bias ? p.bias[gn] : 0.0f);
#pragma unroll
        for (int r = 0; r < 4; ++r) {
          float v = acc[i][j][r] + bv;
          if (RELU) v = fmaxf(v, 0.0f);
          const int m = mb + r;
          const int nb = nl * 2;
          const int phys = (m << 7) + (((nb & ~15) ^ ((m & 7) << 4)) | (nb & 15));
          *(bf16_t*)(Wb + phys) = f2bf(v);
        }
      }
    }
    asm volatile("s_waitcnt lgkmcnt(0)" ::: "memory");
    bf16_t* Cb = (bf16_t*)p.C + (size_t)z * (size_t)p.sC
               + (size_t)(m0 + wr * 128) * p.ldc + (n0 + wc * 64);
#pragma unroll
    for (int q = 0; q < 16; ++q) {
      const int m = q * 8 + (lane >> 3);
      const int c = lane & 7;
      const bf16x8 vv = *(const bf16x8*)(Wb + (m << 7) + (((c ^ (m & 7)) << 4)));
      *(bf16x8*)(Cb + (size_t)m * p.ldc + c * 8) = vv;
    }
  } else {
    char* Wb = ldsc + wave * 16384;
#pragma unroll
    for (int hh = 0; hh < 2; ++hh) {
#pragma unroll
      for (int ii = 0; ii < 4; ++ii) {
        const int i = hh * 4 + ii;
        const int ml = ii * 16 + quad * 4;                        // + r
#pragma unroll
        for (int j = 0; j < 4; ++j) {
          const int nl = (j >> 1) * 32 + (j & 1) * 16 + lr;       // 0..63
          const int gn = n0 + wc * 64 + nl;
          float addv = 0.0f; int mk = 1;
          if constexpr (EPI == EPI_RESID) addv = p.bias ? p.bias[gn] : 0.0f;
          if constexpr (EPI == EPI_SCORES)
            mk = p.mask[(size_t)z * (size_t)p.sMask + gn];
#pragma unroll
          for (int r = 0; r < 4; ++r) {
            const int m = ml + r;
            float v = acc[i][j][r];
            if constexpr (EPI == EPI_SCORES) v = mk ? v * p.scale : -1e9f;
            else v += addv;
            const int nph = nl ^ (((m >> 2) & 3) << 2);
            *(float*)(Wb + m * 256 + nph * 4) = v;
          }
        }
      }
      asm volatile("s_waitcnt lgkmcnt(0)" ::: "memory");
      const int mb = m0 + wr * 128 + hh * 64;
      const int gn0 = n0 + wc * 64 + lr * 4;
#pragma unroll
      for (int q = 0; q < 16; ++q) {
        const int m = q * 4 + quad;
        const int nph = (lr * 4) ^ (((m >> 2) & 3) << 2);
        f32x4 v = *(const f32x4*)(Wb + m * 256 + nph * 4);
        const size_t off = (size_t)z * (size_t)p.sC
                         + (size_t)(mb + m) * p.ldc + gn0;
        if constexpr (EPI == EPI_RESID) {
          const f32x4 rv = *(const f32x4*)(p.resid + off);
          v = v + rv;
        }
        *(f32x4*)((float*)p.C + off) = v;
      }
      if (hh == 0) { asm volatile("s_waitcnt lgkmcnt(0)" ::: "memory"); }
    }
  }
}

template <int EPI, bool RELU>
__global__ __launch_bounds__(512, 2)
void gemm256(GemmP p)
{
  __shared__ __align__(16) char lds_[131072];
  gemm_core<EPI, RELU>(p, blockIdx.x, lds_);
}

// merged launch: blocks [0,n1) run EPI_SCORES on p1; [n1,...) EPI_BF16 on p2.
__global__ __launch_bounds__(512, 2)
void gemm_pair(GemmP p1, int n1, GemmP p2)
{
  __shared__ __align__(16) char lds_[131072];
  if ((int)blockIdx.x < n1) gemm_core<EPI_SCORES, false>(p1, blockIdx.x, lds_);
  else                      gemm_core<EPI_BF16,   false>(p2, blockIdx.x - n1, lds_);
}

// ---------------------------------------------------------------------------
// Shared device bodies: LayerNorm row, softmax row, 32x32 tile transpose.
// ---------------------------------------------------------------------------
__device__ __forceinline__ void ln_body(const float* __restrict__ x,
                                        const float* __restrict__ g,
                                        const float* __restrict__ b,
                                        bf16_t* __restrict__ out,
                                        int row, int t, float* red)
{
  const int wave = t >> 6, lane = t & 63;
  const float4 v = ((const float4*)(x + (size_t)row * DD))[t];

  float s = v.x + v.y + v.z + v.w;
#pragma unroll
  for (int o = 32; o > 0; o >>= 1) s += __shfl_down(s, o);
  if (lane == 0) red[wave] = s;
  __syncthreads();
  const float mu = (red[0] + red[1] + red[2] + red[3]) * (1.0f / DD);

  const float d0 = v.x - mu, d1 = v.y - mu, d2 = v.z - mu, d3 = v.w - mu;
  float ss = d0 * d0 + d1 * d1 + d2 * d2 + d3 * d3;
#pragma unroll
  for (int o = 32; o > 0; o >>= 1) ss += __shfl_down(ss, o);
  if (lane == 0) red[4 + wave] = ss;
  __syncthreads();
  const float var = (red[4] + red[5] + red[6] + red[7]) * (1.0f / DD);
  const float rs  = rsqrtf(var + 1e-5f);

  const float4 gg = ((const float4*)g)[t];
  const float4 bb = ((const float4*)b)[t];
  short4v o;
  o.x = (short)f2bf(d0 * rs * gg.x + bb.x);
  o.y = (short)f2bf(d1 * rs * gg.y + bb.y);
  o.z = (short)f2bf(d2 * rs * gg.z + bb.z);
  o.w = (short)f2bf(d3 * rs * gg.w + bb.w);
  *(short4v*)(out + (size_t)row * DD + t * 4) = o;
}

__global__ __launch_bounds__(256)
void softmax_kernel(float* __restrict__ w, bf16_t* __restrict__ wb)
{
  __shared__ float red[8];
  const size_t rowoff = (size_t)blockIdx.x * SS;
  float* p = w + rowoff;
  const int t = threadIdx.x;
  const int wave = t >> 6, lane = t & 63;
  float4 v0 = ((float4*)p)[t];
  float4 v1 = ((float4*)p)[t + 256];

  float m = fmaxf(fmaxf(fmaxf(v0.x, v0.y), fmaxf(v0.z, v0.w)),
                  fmaxf(fmaxf(v1.x, v1.y), fmaxf(v1.z, v1.w)));
#pragma unroll
  for (int o = 32; o > 0; o >>= 1) m = fmaxf(m, __shfl_down(m, o));
  if (lane == 0) red[wave] = m;
  __syncthreads();
  m = fmaxf(fmaxf(red[0], red[1]), fmaxf(red[2], red[3]));

  v0.x = __expf(v0.x - m); v0.y = __expf(v0.y - m);
  v0.z = __expf(v0.z - m); v0.w = __expf(v0.w - m);
  v1.x = __expf(v1.x - m); v1.y = __expf(v1.y - m);
  v1.z = __expf(v1.z - m); v1.w = __expf(v1.w - m);

  float s = v0.x + v0.y + v0.z + v0.w + v1.x + v1.y + v1.z + v1.w;
#pragma unroll
  for (int o = 32; o > 0; o >>= 1) s += __shfl_down(s, o);
  if (lane == 0) red[4 + wave] = s;
  __syncthreads();
  const float inv = 1.0f / (red[4] + red[5] + red[6] + red[7]);

  v0.x *= inv; v0.y *= inv; v0.z *= inv; v0.w *= inv;
  v1.x *= inv; v1.y *= inv; v1.z *= inv; v1.w *= inv;
  ((float4*)p)[t] = v0;
  ((float4*)p)[t + 256] = v1;

  short4v o0 = { (short)f2bf(v0.x), (short)f2bf(v0.y), (short)f2bf(v0.z), (short)f2bf(v0.w) };
  short4v o1 = { (short)f2bf(v1.x), (short)f2bf(v1.y), (short)f2bf(v1.z), (short)f2bf(v1.w) };
  *(short4v*)(wb + rowoff + t * 4)         = o0;
  *(short4v*)(wb + rowoff + (t + 256) * 4) = o1;
}

template <typename ST>
__device__ __forceinline__ void transpose_body(const ST* __restrict__ in,
                                               bf16_t* __restrict__ out,
                                               int R, int ldin,
                                               long long inB, long long outB,
                                               int xb, int yb, int zb,
                                               int tx, int ty, float* tile)
{
  const size_t zi = (size_t)zb * (size_t)inB;
  const size_t zo = (size_t)zb * (size_t)outB;
  const int c0 = xb * 32, r0 = yb * 32;
#pragma unroll
  for (int k = 0; k < 32; k += 8) {
    ST raw = in[zi + (size_t)(r0 + ty + k) * ldin + (c0 + tx)];
    float v;
    if constexpr (sizeof(ST) == 2) {
      v = __uint_as_float(((unsigned)(unsigned short)raw) << 16);
    } else {
      v = (float)raw;
    }
    tile[(ty + k) * 33 + tx] = v;
  }
  __syncthreads();
#pragma unroll
  for (int k = 0; k < 32; k += 8)
    out[zo + (size_t)(c0 + ty + k) * R + (r0 + tx)] = f2bf(tile[tx * 33 + ty + k]);
}

// ---------------------------------------------------------------------------
// prep: 5 weight transposes (blocks 0..5119) + LN1 rows (blocks 5120..21503)
// ---------------------------------------------------------------------------
__global__ __launch_bounds__(256)
void prep_kernel(const float* __restrict__ Wq, const float* __restrict__ Wk,
                 const float* __restrict__ Wo, const float* __restrict__ W1,
                 const float* __restrict__ W2,
                 bf16_t* __restrict__ WqkT, bf16_t* __restrict__ WoT,
                 bf16_t* __restrict__ W1T, bf16_t* __restrict__ W2T,
                 const float* __restrict__ x, const float* __restrict__ g,
                 const float* __restrict__ b, bf16_t* __restrict__ xn)
{
  __shared__ float smem[32 * 33];
  const int bid = blockIdx.x;
  const int tid = threadIdx.x;
  if (bid < 5120) {
    const int wi = bid >> 10;
    const int rem = bid & 1023;
    const float* src = wi == 0 ? Wq : wi == 1 ? Wk : wi == 2 ? Wo : wi == 3 ? W1 : W2;
    bf16_t* dst = wi == 0 ? WqkT : wi == 1 ? (WqkT + (size_t)DD * DD)
                 : wi == 2 ? WoT : wi == 3 ? W1T : W2T;
    transpose_body<float>(src, dst, DD, DD, 0, 0,
                          rem & 31, rem >> 5, 0, tid & 31, tid >> 5, smem);
  } else {
    ln_body(x, g, b, xn, bid - 5120, tid, smem);
  }
}

__global__ __launch_bounds__(256)
void ln_kernel(const float* __restrict__ x, const float* __restrict__ g,
               const float* __restrict__ b, bf16_t* __restrict__ out)
{
  __shared__ float red[8];
  ln_body(x, g, b, out, blockIdx.x, threadIdx.x, red);
}

// ---------------------------------------------------------------------------
extern "C" void kernel_launch(void* const* d_in, const int* in_sizes, int n_in,
                              void* d_out, int out_size, void* d_ws, size_t ws_size,
                              hipStream_t stream)
{
  const float* x    = (const float*)d_in[0];
  const int*   mask = (const int*)d_in[1];
  const float* ln1g = (const float*)d_in[2];
  const float* ln1b = (const float*)d_in[3];
  const float* Wq   = (const float*)d_in[4];
  const float* bq   = (const float*)d_in[5];
  const float* Wk   = (const float*)d_in[6];
  const float* bk   = (const float*)d_in[7];
  const float* Wo   = (const float*)d_in[8];
  const float* bo   = (const float*)d_in[9];
  const float* ln2g = (const float*)d_in[10];
  const float* ln2b = (const float*)d_in[11];
  const float* W1   = (const float*)d_in[12];
  const float* b1   = (const float*)d_in[13];
  const float* W2   = (const float*)d_in[14];
  const float* b2   = (const float*)d_in[15];

  float* out  = (float*)d_out;                       // (B,S,D) f32, 64MB
  float* wout = out + (size_t)BB * SS * DD;          // (B,S,S) f32, 128MB

  char* ws = (char*)d_ws;
  size_t off = 0;
  auto alloc = [&](size_t bytes) {
    char* p = ws + off; off += (bytes + 255) & ~(size_t)255; return p;
  };
  bf16_t* WqkT = (bf16_t*)alloc((size_t)2 * DD * DD * 2);   // [2048,1024] = WqT ; WkT
  bf16_t* WoT  = (bf16_t*)alloc((size_t)DD * DD * 2);
  bf16_t* W1T  = (bf16_t*)alloc((size_t)DD * DD * 2);
  bf16_t* W2T  = (bf16_t*)alloc((size_t)DD * DD * 2);
  bf16_t* QKb  = (bf16_t*)alloc((size_t)BB * SS * 2 * DD * 2);  // [16384,2048] bf16
  char*   Rwb  = alloc((size_t)64 * 1024 * 1024);               // wbf -> xn2+h
  bf16_t* KWoT = (bf16_t*)alloc((size_t)BB * SS * DD * 2);      // (K@Wo)^T [B,1024,2048]

  bf16_t* wbf = (bf16_t*)Rwb;                      // (B,S,S) bf16, dies after w@KWo
  bf16_t* xn2 = (bf16_t*)Rwb;                      // (B*S,D) bf16 (after wbf dead)
  bf16_t* h   = (bf16_t*)(Rwb + (size_t)32 * 1024 * 1024);  // (B*S,D_FF) bf16

  bf16_t* xn = (bf16_t*)wout;                      // (B*S,D) bf16, dies after QK
  float*  x2 = out;                                // (B*S,D) f32

  const dim3 tb(256);
  const dim3 tg(512);
  const long long SD  = (long long)SS * DD;
  const long long S2  = (long long)SS * SS;
  const long long QKs = (long long)SS * 2 * DD;

  // 1. prep: weights -> transposed bf16 [N][K] (Wq,Wk concatenated) + LN1
  prep_kernel<<<dim3(5120 + BB * SS), tb, 0, stream>>>(
      Wq, Wk, Wo, W1, W2, WqkT, WoT, W1T, W2T, x, ln1g, ln1b, xn);

  // 2. QK = xn @ [Wq|Wk] + [bq|bk]   (bf16, [16384,2048])
  gemm256<EPI_BF16, false><<<dim3(512), tg, 0, stream>>>(GemmP{
      xn, WqkT, QKb, bq, bk, nullptr, nullptr,
      64, 8, 1, 8, DD, DD, DD, 2 * DD, 0, 0, 0, 0, 1.0f});

  // 3. merged: scores (blocks 0..511) + KWoT (512..767).  nchunk = r5 values.
  {
    GemmP ps{QKb, QKb + DD, wout, nullptr, nullptr, nullptr, mask,
             8, 8, BB, 8, DD, 2 * DD, 2 * DD, SS, QKs, QKs, S2, SS, 0.03125f};
    GemmP pk{WoT, QKb + DD, KWoT, nullptr, nullptr, nullptr, nullptr,
             4, 8, BB, 8, DD, DD, 2 * DD, SS, 0, QKs, SD, 0, 1.0f};
    gemm_pair<<<dim3(768), tg, 0, stream>>>(ps, 512, pk);
  }

  // 4. softmax rows -> wout (f32, required output) + wbf (bf16)
  softmax_kernel<<<dim3(BB * SS), tb, 0, stream>>>(wout, wbf);

  // 5. x2 = x + w @ KWoT^T + bo  (f32, into out region)
  gemm256<EPI_RESID, false><<<dim3(256), tg, 0, stream>>>(GemmP{
      wbf, KWoT, x2, bo, nullptr, x, nullptr,
      8, 4, BB, 4, SS, SS, SS, DD, S2, SD, SD, 0, 1.0f});

  // 6. xn2 = LN2(x2)
  ln_kernel<<<dim3(BB * SS), tb, 0, stream>>>(x2, ln2g, ln2b, xn2);

  // 7. h = relu(xn2@W1 + b1)  (bf16)
  gemm256<EPI_BF16, true><<<dim3(256), tg, 0, stream>>>(GemmP{
      xn2, W1T, h, b1, nullptr, nullptr, nullptr,
      64, 4, 1, 4, DD, DD, DD, DD, 0, 0, 0, 0, 1.0f});

  // 8. out = x2 + h@W2 + b2  (f32, elementwise RMW of out region)
  gemm256<EPI_RESID, false><<<dim3(256), tg, 0, stream>>>(GemmP{
      h, W2T, out, b2, nullptr, x2, nullptr,
      64, 4, 1, 4, DD, DD, DD, DD, 0, 0, 0, 0, 1.0f});
}